// Round 4
// baseline (1714.404 us; speedup 1.0000x reference)
//
#include <hip/hip_runtime.h>
#include <math.h>

#define BB 4
#define TT 8
#define CC 128
#define HWW 9216            // 96*96
#define NPG 1179648.0f      // C*H*W per (b,t) group
#define EPS 1e-5f
#define SCALE 0.17677669529663687f   // 1/sqrt(32)

// ws layout in floats (identical to Round 1, proven safe at 557 KB):
#define WS_SUMS 0
#define WS_A    64
#define WS_B    4160
#define WS_M    8256      // M[4][128][128]: M[n][c][c2] = sum_d Wq_n[d,c]*Wk_n[d,c2]
#define WS_G    73792     // G[4][128][128]: G[n][e][c]  = sum_d P[e,n*32+d]*Wv_n[d,c]

typedef __attribute__((ext_vector_type(4))) float f32x4;

__global__ __launch_bounds__(256) void stats_kernel(
    const float* __restrict__ x, const float* __restrict__ pe,
    float* __restrict__ sums)
{
    const int g    = blockIdx.y;
    const int part = blockIdx.x;
    const int tid  = threadIdx.x;
    const int t    = g & 7;
    float s1 = 0.f, s2 = 0.f;
    for (int r = 0; r < 8; ++r) {
        const int c = part * 8 + r;
        const float pec = pe[t * CC + c];
        const float4* row = (const float4*)(x + ((size_t)g * CC + c) * HWW);
        for (int i = tid; i < HWW / 4; i += 256) {
            float4 v = row[i];
            float a = v.x + pec, b = v.y + pec, cc2 = v.z + pec, d = v.w + pec;
            s1 += (a + b) + (cc2 + d);
            s2 += (a * a + b * b) + (cc2 * cc2 + d * d);
        }
    }
    for (int off = 32; off; off >>= 1) {
        s1 += __shfl_down(s1, off);
        s2 += __shfl_down(s2, off);
    }
    __shared__ float red[8];
    const int wid = tid >> 6, lane = tid & 63;
    if (lane == 0) { red[wid] = s1; red[4 + wid] = s2; }
    __syncthreads();
    if (tid == 0) {
        atomicAdd(&sums[g * 2 + 0], red[0] + red[1] + red[2] + red[3]);
        atomicAdd(&sums[g * 2 + 1], red[4] + red[5] + red[6] + red[7]);
    }
}

__global__ void finalize_kernel(
    const float* __restrict__ pe, const float* __restrict__ nw,
    const float* __restrict__ nb, float* ws)
{
    const int g = blockIdx.x;
    const int c = threadIdx.x;
    const float inv = 1.0f / NPG;
    const float mean = ws[WS_SUMS + g * 2 + 0] * inv;
    const float var  = ws[WS_SUMS + g * 2 + 1] * inv - mean * mean;
    const float rstd = rsqrtf(var + EPS);
    const int t = g & 7;
    const float a = rstd * nw[c];
    ws[WS_A + g * CC + c] = a;
    ws[WS_B + g * CC + c] = (pe[t * CC + c] - mean) * a + nb[c];
}

__global__ __launch_bounds__(256) void precompute_kernel(
    const float* __restrict__ qkv_w, const float* __restrict__ proj_w,
    float* __restrict__ ws)
{
    const int id = blockIdx.x * 256 + threadIdx.x;  // 131072 threads
    const int half = id >> 16;
    const int j = id & 65535;
    const int n = j >> 14, rem = j & 16383, a = rem >> 7, c = rem & 127;
    float s = 0.f;
    if (half == 0) {
        #pragma unroll
        for (int d = 0; d < 32; ++d)
            s += qkv_w[(n * 32 + d) * CC + a] * qkv_w[(CC + n * 32 + d) * CC + c];
        ws[WS_M + j] = s;
    } else {
        #pragma unroll
        for (int d = 0; d < 32; ++d)
            s += proj_w[a * CC + n * 32 + d] * qkv_w[(2 * CC + n * 32 + d) * CC + c];
        ws[WS_G + j] = s;
    }
}

// Fused: r = half of M_n^T xn7 per thread -> scores (halves combined via LDS)
// -> softmax (per-thread, redundant across halves) -> xbar half (reuses r regs)
// -> y = G xbar via rotated 16-row slices into LDS accumulator.
// 512 threads: wave w = (head n = w>>1, c-half h = w&1); lane = position.
__global__ __launch_bounds__(512, 4) void fused_kernel(
    const float* __restrict__ x, const float* __restrict__ ws,
    float* __restrict__ out)
{
    __shared__ __align__(16) float xn[CC][64];    // 32 KB: xn[c][pos]
    __shared__ __align__(16) float yt[CC][64];    // 32 KB: y accumulator
    __shared__ float sbuf[8][64];                 // 2 KB: score half-partials

    const int tid  = threadIdx.x;
    const int lane = tid & 63;          // position
    const int w    = tid >> 6;          // wave 0..7
    const int n    = __builtin_amdgcn_readfirstlane(w >> 1);   // head (wave-uniform)
    const int h    = __builtin_amdgcn_readfirstlane(w & 1);    // c-half (wave-uniform)
    const int b    = blockIdx.y;
    const int hw0  = blockIdx.x * 64;

    const float* Mn = ws + WS_M + (n * CC) * CC + h * 64;   // M[n][c][h*64+j]
    const float* Gn = ws + WS_G + (n * CC) * CC + h * 64;   // G[n][e][h*64+j]

    // cooperative tile stage: xn[c][p] normalized, all 512 threads
    auto stage = [&](int t) {
        const int g = b * TT + t;
        const float* Ac = ws + WS_A + g * CC;
        const float* Bc = ws + WS_B + g * CC;
        const size_t base = (size_t)(g * CC) * HWW + hw0;
        #pragma unroll
        for (int i = 0; i < 4; ++i) {
            const int quad = tid + i * 512;      // 0..2047 = 128 rows x 16 quads
            const int c = quad >> 4, q = quad & 15;
            f32x4 v = *(const f32x4*)(x + base + (size_t)c * HWW + q * 4);
            const float a = Ac[c], bb = Bc[c];
            f32x4 rr;
            rr.x = fmaf(v.x, a, bb); rr.y = fmaf(v.y, a, bb);
            rr.z = fmaf(v.z, a, bb); rr.w = fmaf(v.w, a, bb);
            *(f32x4*)&xn[c][q * 4] = rr;
        }
    };

    // ---- phase 0/1: r[j] = sum_c M_n[c][h*64+j] * xn7[c][p] ----
    stage(7);
    __syncthreads();

    float r[64];
    #pragma unroll
    for (int j = 0; j < 64; ++j) r[j] = 0.f;
    for (int c = 0; c < CC; ++c) {
        const float xv = xn[c][lane];
        const float* Mrow = Mn + c * CC;
        #pragma unroll
        for (int j = 0; j < 64; ++j) r[j] = fmaf(Mrow[j], xv, r[j]);
    }

    // ---- phase 2: sc[t] = sum_c2 r_full[c2] * xn_t[c2][p], halves via sbuf ----
    float sc[TT];
    for (int t = 0; t < TT; ++t) {
        __syncthreads();             // prior xn reads done
        stage(t);
        __syncthreads();
        float s0 = 0.f, s1 = 0.f, s2 = 0.f, s3 = 0.f;
        #pragma unroll
        for (int j = 0; j < 64; j += 4) {
            s0 = fmaf(r[j + 0], xn[h * 64 + j + 0][lane], s0);
            s1 = fmaf(r[j + 1], xn[h * 64 + j + 1][lane], s1);
            s2 = fmaf(r[j + 2], xn[h * 64 + j + 2][lane], s2);
            s3 = fmaf(r[j + 3], xn[h * 64 + j + 3][lane], s3);
        }
        sbuf[w][lane] = (s0 + s1) + (s2 + s3);
        __syncthreads();
        sc[t] = sbuf[n * 2][lane] + sbuf[n * 2 + 1][lane];
    }

    // ---- phase 3: softmax over t (redundant across h, consistent) ----
    float mx = sc[0];
    #pragma unroll
    for (int t = 1; t < TT; ++t) mx = fmaxf(mx, sc[t]);
    float wgt[TT], sum = 0.f;
    #pragma unroll
    for (int t = 0; t < TT; ++t) { wgt[t] = __expf((sc[t] - mx) * SCALE); sum += wgt[t]; }
    const float inv = 1.0f / sum;
    #pragma unroll
    for (int t = 0; t < TT; ++t) wgt[t] *= inv;

    // ---- phase 4: xbar[j] = sum_t wgt[t] * xn_t[h*64+j][p]  (reuse r regs) ----
    #pragma unroll
    for (int j = 0; j < 64; ++j) r[j] = 0.f;
    for (int t = 0; t < TT; ++t) {
        __syncthreads();
        stage(t);
        __syncthreads();
        const float wt = wgt[t];
        #pragma unroll
        for (int j = 0; j < 64; ++j) r[j] = fmaf(wt, xn[h * 64 + j][lane], r[j]);
    }

    // ---- phase 5: yt[e][p] += sum_j G_n[e][h*64+j] * xbar[j], rotated slices ----
    __syncthreads();
    for (int i = tid; i < CC * 64; i += 512) ((float*)yt)[i] = 0.f;
    __syncthreads();
    for (int round = 0; round < 8; ++round) {
        const int e0 = ((w + round) & 7) * 16;
        for (int e = e0; e < e0 + 16; ++e) {
            const float* Grow = Gn + e * CC;
            float y0 = 0.f, y1 = 0.f, y2 = 0.f, y3 = 0.f;
            #pragma unroll
            for (int j = 0; j < 64; j += 4) {
                y0 = fmaf(Grow[j + 0], r[j + 0], y0);
                y1 = fmaf(Grow[j + 1], r[j + 1], y1);
                y2 = fmaf(Grow[j + 2], r[j + 2], y2);
                y3 = fmaf(Grow[j + 3], r[j + 3], y3);
            }
            yt[e][lane] += (y0 + y1) + (y2 + y3);
        }
        __syncthreads();
    }

    // ---- writeout ----
    #pragma unroll
    for (int i = 0; i < 4; ++i) {
        const int quad = tid + i * 512;
        const int e = quad >> 4, q = quad & 15;
        *(f32x4*)(out + (size_t)(b * CC + e) * HWW + hw0 + q * 4) =
            *(const f32x4*)&yt[e][q * 4];
    }
}

extern "C" void kernel_launch(void* const* d_in, const int* in_sizes, int n_in,
                              void* d_out, int out_size, void* d_ws, size_t ws_size,
                              hipStream_t stream) {
    const float* x      = (const float*)d_in[0];
    const float* pe     = (const float*)d_in[1];
    const float* nw     = (const float*)d_in[2];
    const float* nb     = (const float*)d_in[3];
    const float* qkv_w  = (const float*)d_in[4];
    const float* proj_w = (const float*)d_in[5];
    float* out = (float*)d_out;
    float* ws  = (float*)d_ws;

    hipMemsetAsync(ws, 0, 64 * sizeof(float), stream);
    stats_kernel<<<dim3(16, 32), 256, 0, stream>>>(x, pe, ws);
    finalize_kernel<<<32, 128, 0, stream>>>(pe, nw, nb, ws);
    precompute_kernel<<<512, 256, 0, stream>>>(qkv_w, proj_w, ws);
    fused_kernel<<<dim3(HWW / 64, BB), 512, 0, stream>>>(x, ws, out);
}

// Round 5
// 1678.256 us; speedup vs baseline: 1.0215x; 1.0215x over previous
//
#include <hip/hip_runtime.h>
#include <math.h>

#define BB 4
#define TT 8
#define CC 128
#define HWW 9216            // 96*96
#define NPG 1179648.0f      // C*H*W per (b,t) group
#define EPS 1e-5f
#define SCALE 0.17677669529663687f   // 1/sqrt(32)

// ws layout in floats (identical to Round 1/4, proven safe):
#define WS_SUMS 0
#define WS_A    64
#define WS_B    4160
#define WS_M    8256      // M[4][128][128]: M[n][c][c2] = sum_d Wq_n[d,c]*Wk_n[d,c2]
#define WS_G    73792     // G[4][128][128]: G[n][e][c]  = sum_d P[e,n*32+d]*Wv_n[d,c]

typedef __attribute__((ext_vector_type(4))) float f32x4;

__global__ __launch_bounds__(256) void stats_kernel(
    const float* __restrict__ x, const float* __restrict__ pe,
    float* __restrict__ sums)
{
    const int g    = blockIdx.y;
    const int part = blockIdx.x;
    const int tid  = threadIdx.x;
    const int t    = g & 7;
    float s1 = 0.f, s2 = 0.f;
    for (int r = 0; r < 8; ++r) {
        const int c = part * 8 + r;
        const float pec = pe[t * CC + c];
        const float4* row = (const float4*)(x + ((size_t)g * CC + c) * HWW);
        for (int i = tid; i < HWW / 4; i += 256) {
            float4 v = row[i];
            float a = v.x + pec, b = v.y + pec, cc2 = v.z + pec, d = v.w + pec;
            s1 += (a + b) + (cc2 + d);
            s2 += (a * a + b * b) + (cc2 * cc2 + d * d);
        }
    }
    for (int off = 32; off; off >>= 1) {
        s1 += __shfl_down(s1, off);
        s2 += __shfl_down(s2, off);
    }
    __shared__ float red[8];
    const int wid = tid >> 6, lane = tid & 63;
    if (lane == 0) { red[wid] = s1; red[4 + wid] = s2; }
    __syncthreads();
    if (tid == 0) {
        atomicAdd(&sums[g * 2 + 0], red[0] + red[1] + red[2] + red[3]);
        atomicAdd(&sums[g * 2 + 1], red[4] + red[5] + red[6] + red[7]);
    }
}

__global__ void finalize_kernel(
    const float* __restrict__ pe, const float* __restrict__ nw,
    const float* __restrict__ nb, float* ws)
{
    const int g = blockIdx.x;
    const int c = threadIdx.x;
    const float inv = 1.0f / NPG;
    const float mean = ws[WS_SUMS + g * 2 + 0] * inv;
    const float var  = ws[WS_SUMS + g * 2 + 1] * inv - mean * mean;
    const float rstd = rsqrtf(var + EPS);
    const int t = g & 7;
    const float a = rstd * nw[c];
    ws[WS_A + g * CC + c] = a;
    ws[WS_B + g * CC + c] = (pe[t * CC + c] - mean) * a + nb[c];
}

__global__ __launch_bounds__(256) void precompute_kernel(
    const float* __restrict__ qkv_w, const float* __restrict__ proj_w,
    float* __restrict__ ws)
{
    const int id = blockIdx.x * 256 + threadIdx.x;  // 131072 threads
    const int half = id >> 16;
    const int j = id & 65535;
    const int n = j >> 14, rem = j & 16383, a = rem >> 7, c = rem & 127;
    float s = 0.f;
    if (half == 0) {
        #pragma unroll
        for (int d = 0; d < 32; ++d)
            s += qkv_w[(n * 32 + d) * CC + a] * qkv_w[(CC + n * 32 + d) * CC + c];
        ws[WS_M + j] = s;
    } else {
        #pragma unroll
        for (int d = 0; d < 32; ++d)
            s += proj_w[a * CC + n * 32 + d] * qkv_w[(2 * CC + n * 32 + d) * CC + c];
        ws[WS_G + j] = s;
    }
}

// Fused, single-pass over x (online softmax):
//   stage t=7 -> r = half(M_n^T xn7) -> sc7 -> init (m,l,xb)
//   stream t=0..6: stage once, score, online-rescale accumulate xb
//   xb /= l -> y = G xbar via rotated 16-row slices into LDS accumulator.
// 512 threads: wave w = (head n = w>>1, c-half h = w&1); lane = position.
__global__ __launch_bounds__(512, 4) void fused_kernel(
    const float* __restrict__ x, const float* __restrict__ ws,
    float* __restrict__ out)
{
    __shared__ __align__(16) float xn[CC][64];    // 32 KB: xn[c][pos]
    __shared__ __align__(16) float yt[CC][64];    // 32 KB: y accumulator
    __shared__ float sbuf[8][64];                 // 2 KB: score half-partials

    const int tid  = threadIdx.x;
    const int lane = tid & 63;          // position
    const int w    = tid >> 6;          // wave 0..7
    const int n    = __builtin_amdgcn_readfirstlane(w >> 1);   // head
    const int h    = __builtin_amdgcn_readfirstlane(w & 1);    // c-half
    const int b    = blockIdx.y;
    const int hw0  = blockIdx.x * 64;

    const float* Mn = ws + WS_M + (n * CC) * CC + h * 64;   // M[n][c][h*64+j]
    const float* Gn = ws + WS_G + (n * CC) * CC + h * 64;   // G[n][e][h*64+j]

    // cooperative tile stage: xn[c][p] normalized, all 512 threads
    auto stage = [&](int t) {
        const int g = b * TT + t;
        const float* Ac = ws + WS_A + g * CC;
        const float* Bc = ws + WS_B + g * CC;
        const size_t base = (size_t)(g * CC) * HWW + hw0;
        #pragma unroll
        for (int i = 0; i < 4; ++i) {
            const int quad = tid + i * 512;      // 0..2047 = 128 rows x 16 quads
            const int c = quad >> 4, q = quad & 15;
            f32x4 v = *(const f32x4*)(x + base + (size_t)c * HWW + q * 4);
            const float a = Ac[c], bb = Bc[c];
            f32x4 rr;
            rr.x = fmaf(v.x, a, bb); rr.y = fmaf(v.y, a, bb);
            rr.z = fmaf(v.z, a, bb); rr.w = fmaf(v.w, a, bb);
            *(f32x4*)&xn[c][q * 4] = rr;
        }
    };

    // half-score for current tile: sum_j r[j] * xn[h*64+j][p]
    float r[64];
    auto half_score = [&]() -> float {
        float s0 = 0.f, s1 = 0.f, s2 = 0.f, s3 = 0.f;
        #pragma unroll
        for (int j = 0; j < 64; j += 4) {
            s0 = fmaf(r[j + 0], xn[h * 64 + j + 0][lane], s0);
            s1 = fmaf(r[j + 1], xn[h * 64 + j + 1][lane], s1);
            s2 = fmaf(r[j + 2], xn[h * 64 + j + 2][lane], s2);
            s3 = fmaf(r[j + 3], xn[h * 64 + j + 3][lane], s3);
        }
        return (s0 + s1) + (s2 + s3);
    };

    // ---- t=7: r = half of M_n^T xn7, then sc7 from the same tile ----
    stage(7);
    __syncthreads();

    #pragma unroll
    for (int j = 0; j < 64; ++j) r[j] = 0.f;
    for (int c = 0; c < CC; ++c) {
        const float xv = xn[c][lane];
        const float* Mrow = Mn + c * CC;
        #pragma unroll
        for (int j = 0; j < 64; ++j) r[j] = fmaf(Mrow[j], xv, r[j]);
    }

    sbuf[w][lane] = half_score();
    __syncthreads();
    float sc = sbuf[n * 2][lane] + sbuf[n * 2 + 1][lane];

    // online-softmax state, initialized with t=7 (tile still resident)
    float m = sc, l = 1.f;
    float xb[64];
    #pragma unroll
    for (int j = 0; j < 64; ++j) xb[j] = xn[h * 64 + j][lane];

    // ---- stream t=0..6: score + online accumulate, one tile load each ----
    for (int t = 0; t < 7; ++t) {
        __syncthreads();             // all xn/sbuf reads of previous tile done
        stage(t);
        __syncthreads();
        sbuf[w][lane] = half_score();
        __syncthreads();
        sc = sbuf[n * 2][lane] + sbuf[n * 2 + 1][lane];
        const float mnew  = fmaxf(m, sc);
        const float alpha = __expf((m - mnew) * SCALE);
        const float e     = __expf((sc - mnew) * SCALE);
        l = l * alpha + e;
        m = mnew;
        #pragma unroll
        for (int j = 0; j < 64; ++j)
            xb[j] = fmaf(xn[h * 64 + j][lane], e, xb[j] * alpha);
    }

    const float invl = 1.0f / l;
    #pragma unroll
    for (int j = 0; j < 64; ++j) xb[j] *= invl;

    // ---- output: yt[e][p] += sum_j G_n[e][h*64+j] * xb[j], rotated slices ----
    __syncthreads();
    for (int i = tid; i < CC * 64; i += 512) ((float*)yt)[i] = 0.f;
    __syncthreads();
    for (int round = 0; round < 8; ++round) {
        const int e0 = ((w + round) & 7) * 16;
        for (int e = e0; e < e0 + 16; ++e) {
            const float* Grow = Gn + e * CC;
            float y0 = 0.f, y1 = 0.f, y2 = 0.f, y3 = 0.f;
            #pragma unroll
            for (int j = 0; j < 64; j += 4) {
                y0 = fmaf(Grow[j + 0], xb[j + 0], y0);
                y1 = fmaf(Grow[j + 1], xb[j + 1], y1);
                y2 = fmaf(Grow[j + 2], xb[j + 2], y2);
                y3 = fmaf(Grow[j + 3], xb[j + 3], y3);
            }
            yt[e][lane] += (y0 + y1) + (y2 + y3);
        }
        __syncthreads();
    }

    // ---- writeout ----
    #pragma unroll
    for (int i = 0; i < 4; ++i) {
        const int quad = tid + i * 512;
        const int e = quad >> 4, q = quad & 15;
        *(f32x4*)(out + (size_t)(b * CC + e) * HWW + hw0 + q * 4) =
            *(const f32x4*)&yt[e][q * 4];
    }
}

extern "C" void kernel_launch(void* const* d_in, const int* in_sizes, int n_in,
                              void* d_out, int out_size, void* d_ws, size_t ws_size,
                              hipStream_t stream) {
    const float* x      = (const float*)d_in[0];
    const float* pe     = (const float*)d_in[1];
    const float* nw     = (const float*)d_in[2];
    const float* nb     = (const float*)d_in[3];
    const float* qkv_w  = (const float*)d_in[4];
    const float* proj_w = (const float*)d_in[5];
    float* out = (float*)d_out;
    float* ws  = (float*)d_ws;

    hipMemsetAsync(ws, 0, 64 * sizeof(float), stream);
    stats_kernel<<<dim3(16, 32), 256, 0, stream>>>(x, pe, ws);
    finalize_kernel<<<32, 128, 0, stream>>>(pe, nw, nb, ws);
    precompute_kernel<<<512, 256, 0, stream>>>(qkv_w, proj_w, ws);
    fused_kernel<<<dim3(HWW / 64, BB), 512, 0, stream>>>(x, ws, out);
}

// Round 6
// 822.997 us; speedup vs baseline: 2.0831x; 2.0392x over previous
//
#include <hip/hip_runtime.h>
#include <math.h>

#define BB 4
#define TT 8
#define CC 128
#define HWW 9216            // 96*96
#define NPG 1179648.0f      // C*H*W per (b,t) group
#define EPS 1e-5f
#define SCALE 0.17677669529663687f   // 1/sqrt(32)

// ws layout in floats (identical to Round 1/4/5, proven safe):
#define WS_SUMS 0
#define WS_A    64
#define WS_B    4160
#define WS_M    8256      // M[4][128][128]: M[n][c][c2] = sum_d Wq_n[d,c]*Wk_n[d,c2]
#define WS_G    73792     // G[4][128][128]: G[n][e][c]  = sum_d P[e,n*32+d]*Wv_n[d,c]

typedef __attribute__((ext_vector_type(4))) float f32x4;

__global__ __launch_bounds__(256) void stats_kernel(
    const float* __restrict__ x, const float* __restrict__ pe,
    float* __restrict__ sums)
{
    const int g    = blockIdx.y;
    const int part = blockIdx.x;
    const int tid  = threadIdx.x;
    const int t    = g & 7;
    float s1 = 0.f, s2 = 0.f;
    for (int r = 0; r < 8; ++r) {
        const int c = part * 8 + r;
        const float pec = pe[t * CC + c];
        const float4* row = (const float4*)(x + ((size_t)g * CC + c) * HWW);
        for (int i = tid; i < HWW / 4; i += 256) {
            float4 v = row[i];
            float a = v.x + pec, b = v.y + pec, cc2 = v.z + pec, d = v.w + pec;
            s1 += (a + b) + (cc2 + d);
            s2 += (a * a + b * b) + (cc2 * cc2 + d * d);
        }
    }
    for (int off = 32; off; off >>= 1) {
        s1 += __shfl_down(s1, off);
        s2 += __shfl_down(s2, off);
    }
    __shared__ float red[8];
    const int wid = tid >> 6, lane = tid & 63;
    if (lane == 0) { red[wid] = s1; red[4 + wid] = s2; }
    __syncthreads();
    if (tid == 0) {
        atomicAdd(&sums[g * 2 + 0], red[0] + red[1] + red[2] + red[3]);
        atomicAdd(&sums[g * 2 + 1], red[4] + red[5] + red[6] + red[7]);
    }
}

__global__ void finalize_kernel(
    const float* __restrict__ pe, const float* __restrict__ nw,
    const float* __restrict__ nb, float* ws)
{
    const int g = blockIdx.x;
    const int c = threadIdx.x;
    const float inv = 1.0f / NPG;
    const float mean = ws[WS_SUMS + g * 2 + 0] * inv;
    const float var  = ws[WS_SUMS + g * 2 + 1] * inv - mean * mean;
    const float rstd = rsqrtf(var + EPS);
    const int t = g & 7;
    const float a = rstd * nw[c];
    ws[WS_A + g * CC + c] = a;
    ws[WS_B + g * CC + c] = (pe[t * CC + c] - mean) * a + nb[c];
}

__global__ __launch_bounds__(256) void precompute_kernel(
    const float* __restrict__ qkv_w, const float* __restrict__ proj_w,
    float* __restrict__ ws)
{
    const int id = blockIdx.x * 256 + threadIdx.x;  // 131072 threads
    const int half = id >> 16;
    const int j = id & 65535;
    const int n = j >> 14, rem = j & 16383, a = rem >> 7, c = rem & 127;
    float s = 0.f;
    if (half == 0) {
        #pragma unroll
        for (int d = 0; d < 32; ++d)
            s += qkv_w[(n * 32 + d) * CC + a] * qkv_w[(CC + n * 32 + d) * CC + c];
        ws[WS_M + j] = s;
    } else {
        #pragma unroll
        for (int d = 0; d < 32; ++d)
            s += proj_w[a * CC + n * 32 + d] * qkv_w[(2 * CC + n * 32 + d) * CC + c];
        ws[WS_G + j] = s;
    }
}

// Fused, single-pass over x (online softmax):
//   stage t=7 -> r = half(M_n^T xn7) -> sc7 -> init (m,l,xb)
//   stream t=0..6: stage once, score, online-rescale accumulate xb
//   xb /= l -> y = G xbar via rotated 16-row slices into LDS accumulator.
// 512 threads: wave w = (head n = w>>1, c-half h = w&1); lane = position.
// NOTE: no second __launch_bounds__ arg — (512,4) forced VGPR=64 and spilled
// r[64]/xb[64] to scratch (R5: FETCH 2 GB, WRITE 553 MB, all spill traffic).
__global__ __launch_bounds__(512) void fused_kernel(
    const float* __restrict__ x, const float* __restrict__ ws,
    float* __restrict__ out)
{
    __shared__ __align__(16) float xn[CC][64];    // 32 KB: xn[c][pos]
    __shared__ __align__(16) float yt[CC][64];    // 32 KB: y accumulator
    __shared__ float sbuf[8][64];                 // 2 KB: score half-partials

    const int tid  = threadIdx.x;
    const int lane = tid & 63;          // position
    const int w    = tid >> 6;          // wave 0..7
    const int n    = __builtin_amdgcn_readfirstlane(w >> 1);   // head
    const int h    = __builtin_amdgcn_readfirstlane(w & 1);    // c-half
    const int b    = blockIdx.y;
    const int hw0  = blockIdx.x * 64;

    const float* Mn = ws + WS_M + (n * CC) * CC + h * 64;   // M[n][c][h*64+j]
    const float* Gn = ws + WS_G + (n * CC) * CC + h * 64;   // G[n][e][h*64+j]

    // cooperative tile stage: xn[c][p] normalized, all 512 threads
    auto stage = [&](int t) {
        const int g = b * TT + t;
        const float* Ac = ws + WS_A + g * CC;
        const float* Bc = ws + WS_B + g * CC;
        const size_t base = (size_t)(g * CC) * HWW + hw0;
        #pragma unroll
        for (int i = 0; i < 4; ++i) {
            const int quad = tid + i * 512;      // 0..2047 = 128 rows x 16 quads
            const int c = quad >> 4, q = quad & 15;
            f32x4 v = *(const f32x4*)(x + base + (size_t)c * HWW + q * 4);
            const float a = Ac[c], bb = Bc[c];
            f32x4 rr;
            rr.x = fmaf(v.x, a, bb); rr.y = fmaf(v.y, a, bb);
            rr.z = fmaf(v.z, a, bb); rr.w = fmaf(v.w, a, bb);
            *(f32x4*)&xn[c][q * 4] = rr;
        }
    };

    // half-score for current tile: sum_j r[j] * xn[h*64+j][p]
    float r[64];
    auto half_score = [&]() -> float {
        float s0 = 0.f, s1 = 0.f, s2 = 0.f, s3 = 0.f;
        #pragma unroll
        for (int j = 0; j < 64; j += 4) {
            s0 = fmaf(r[j + 0], xn[h * 64 + j + 0][lane], s0);
            s1 = fmaf(r[j + 1], xn[h * 64 + j + 1][lane], s1);
            s2 = fmaf(r[j + 2], xn[h * 64 + j + 2][lane], s2);
            s3 = fmaf(r[j + 3], xn[h * 64 + j + 3][lane], s3);
        }
        return (s0 + s1) + (s2 + s3);
    };

    // ---- t=7: r = half of M_n^T xn7, then sc7 from the same tile ----
    stage(7);
    __syncthreads();

    #pragma unroll
    for (int j = 0; j < 64; ++j) r[j] = 0.f;
    for (int c = 0; c < CC; ++c) {
        const float xv = xn[c][lane];
        const float* Mrow = Mn + c * CC;
        #pragma unroll
        for (int j = 0; j < 64; ++j) r[j] = fmaf(Mrow[j], xv, r[j]);
    }

    sbuf[w][lane] = half_score();
    __syncthreads();
    float sc = sbuf[n * 2][lane] + sbuf[n * 2 + 1][lane];

    // online-softmax state, initialized with t=7 (tile still resident)
    float m = sc, l = 1.f;
    float xb[64];
    #pragma unroll
    for (int j = 0; j < 64; ++j) xb[j] = xn[h * 64 + j][lane];

    // ---- stream t=0..6: score + online accumulate, one tile load each ----
    for (int t = 0; t < 7; ++t) {
        __syncthreads();             // all xn/sbuf reads of previous tile done
        stage(t);
        __syncthreads();
        sbuf[w][lane] = half_score();
        __syncthreads();
        sc = sbuf[n * 2][lane] + sbuf[n * 2 + 1][lane];
        const float mnew  = fmaxf(m, sc);
        const float alpha = __expf((m - mnew) * SCALE);
        const float e     = __expf((sc - mnew) * SCALE);
        l = l * alpha + e;
        m = mnew;
        #pragma unroll
        for (int j = 0; j < 64; ++j)
            xb[j] = fmaf(xn[h * 64 + j][lane], e, xb[j] * alpha);
    }

    const float invl = 1.0f / l;
    #pragma unroll
    for (int j = 0; j < 64; ++j) xb[j] *= invl;

    // ---- output: yt[e][p] += sum_j G_n[e][h*64+j] * xb[j], rotated slices ----
    __syncthreads();
    for (int i = tid; i < CC * 64; i += 512) ((float*)yt)[i] = 0.f;
    __syncthreads();
    for (int round = 0; round < 8; ++round) {
        const int e0 = ((w + round) & 7) * 16;
        for (int e = e0; e < e0 + 16; ++e) {
            const float* Grow = Gn + e * CC;
            float y0 = 0.f, y1 = 0.f, y2 = 0.f, y3 = 0.f;
            #pragma unroll
            for (int j = 0; j < 64; j += 4) {
                y0 = fmaf(Grow[j + 0], xb[j + 0], y0);
                y1 = fmaf(Grow[j + 1], xb[j + 1], y1);
                y2 = fmaf(Grow[j + 2], xb[j + 2], y2);
                y3 = fmaf(Grow[j + 3], xb[j + 3], y3);
            }
            yt[e][lane] += (y0 + y1) + (y2 + y3);
        }
        __syncthreads();
    }

    // ---- writeout ----
    #pragma unroll
    for (int i = 0; i < 4; ++i) {
        const int quad = tid + i * 512;
        const int e = quad >> 4, q = quad & 15;
        *(f32x4*)(out + (size_t)(b * CC + e) * HWW + hw0 + q * 4) =
            *(const f32x4*)&yt[e][q * 4];
    }
}

extern "C" void kernel_launch(void* const* d_in, const int* in_sizes, int n_in,
                              void* d_out, int out_size, void* d_ws, size_t ws_size,
                              hipStream_t stream) {
    const float* x      = (const float*)d_in[0];
    const float* pe     = (const float*)d_in[1];
    const float* nw     = (const float*)d_in[2];
    const float* nb     = (const float*)d_in[3];
    const float* qkv_w  = (const float*)d_in[4];
    const float* proj_w = (const float*)d_in[5];
    float* out = (float*)d_out;
    float* ws  = (float*)d_ws;

    hipMemsetAsync(ws, 0, 64 * sizeof(float), stream);
    stats_kernel<<<dim3(16, 32), 256, 0, stream>>>(x, pe, ws);
    finalize_kernel<<<32, 128, 0, stream>>>(pe, nw, nb, ws);
    precompute_kernel<<<512, 256, 0, stream>>>(qkv_w, proj_w, ws);
    fused_kernel<<<dim3(HWW / 64, BB), 512, 0, stream>>>(x, ws, out);
}